// Round 7
// baseline (1748.383 us; speedup 1.0000x reference)
//
#include <hip/hip_runtime.h>
#include <hip/hip_bf16.h>
#include <stdint.h>

// Problem constants
#define NN 32768
#define KNBR 32

typedef __attribute__((ext_vector_type(8))) short short8;
typedef __attribute__((ext_vector_type(4))) float f32x4;

__device__ __forceinline__ unsigned int f2bf(float x) {
    union { float f; unsigned int u; } c; c.f = x;
    return (c.u + 0x7FFFu + ((c.u >> 16) & 1u)) >> 16;
}
__device__ __forceinline__ unsigned int pk2(float a, float b) {
    return f2bf(a) | (f2bf(b) << 16);
}
// cheap round-half-up bf16 pack (validated: absmax 0.125 in r2-r6)
__device__ __forceinline__ unsigned int pkr(float a, float b) {
    unsigned ua = __float_as_uint(a) + 0x8000u;
    unsigned ub = __float_as_uint(b) + 0x8000u;
    return (ua >> 16) | (ub & 0xFFFF0000u);
}
__device__ __forceinline__ float silu_f(float x) {
    return x / (1.0f + __expf(-x));
}

// ---------------------------------------------------------------------------
// Kernel 1: convert W_f2, W_nb, W_c (f32 [256][256]) into bf16 MFMA B-frag
// layout: frag q = (kt*16 + ntg)*64 + lane holds
// B[k = kt*32 + (lane>>4)*8 + i][col = ntg*16 + (lane&15)], i=0..7.
// ---------------------------------------------------------------------------
__global__ void prep_weights(const float* __restrict__ Wf2,
                             const float* __restrict__ Wnb,
                             const float* __restrict__ Wc,
                             uint4* __restrict__ ws_out) {
    int t = blockIdx.x * 256 + threadIdx.x;   // 0..24575
    int w = t >> 13;
    int q = t & 8191;
    int kt = q >> 10;
    int nt = (q >> 6) & 15;
    int lane = q & 63;
    int k0 = kt * 32 + ((lane >> 4) << 3);
    int col = nt * 16 + (lane & 15);
    const float* src = (w == 0) ? Wf2 : (w == 1) ? Wnb : Wc;
    const float* p = src + (size_t)k0 * 256 + col;
    uint4 o;
    o.x = pk2(p[0],        p[256]);
    o.y = pk2(p[512],      p[768]);
    o.z = pk2(p[1024],     p[1280]);
    o.w = pk2(p[1536],     p[1792]);
    ws_out[t] = o;
}

// ---------------------------------------------------------------------------
// Kernel 2: fused edge pipeline. Weights RESIDENT in LDS. 1024 thr = 16 waves
// (4M x 4N). f-staging: thread owns FIXED k-octet (coefs in 40 VGPRs, zero
// LDS coefficient reads); the 2-wave cohort (tid>>7 == kt) stages f for its
// step, rotating over the tile's 8 steps. E: 512 threads, 1 uint4 write each.
// Staging writes XOR-swizzled; A-frag reads use lane^((lane>>4)<<2).
// Step: [prefetch g+2 | A reads | bar1 | B reads + 8 MFMA | stage g+1 |
//        (epilogue) | bar2] -- raw barriers, only lgkmcnt drained.
// ---------------------------------------------------------------------------
__global__ __launch_bounds__(1024, 4) void msg_kernel(
        const float* __restrict__ nbr,    // h_neighbors [N*K, 256]
        const float* __restrict__ diff,   // differences [N*K, 4]
        const float* __restrict__ Wf1,    // [4,256]
        const float* __restrict__ b1,     // [256]
        const float* __restrict__ b2,     // b_f2 [256]
        const float* __restrict__ bnb,    // b_nb [256]
        const uint4* __restrict__ wf2_g,  // frag bf16, 8192 uint4
        const uint4* __restrict__ wnb_g,  // frag bf16, 8192 uint4
        float* __restrict__ msg_out)      // [N,256] f32
{
    __shared__ uint4 w2l[4096];        // 64KB  Wf2, this block's 128 cols
    __shared__ uint4 wnl[4096];        // 64KB  Wnb
    __shared__ uint4 fbuf[512];        // 8KB   f A-frags, one K-step
    __shared__ uint4 ebuf[512];        // 8KB   E A-frags, one K-step

    const int tid  = threadIdx.x;
    const int lane = tid & 63;
    const int wid  = tid >> 6;        // 0..15
    const int wm   = wid >> 2;        // 0..3  (32-row slice)
    const int wn   = wid & 3;         // 0..3  (32-col slice)
    const int xcd  = blockIdx.x & 7;
    const int yy   = blockIdx.x >> 3;
    const int chalf = yy & 1;
    const int rgrp  = xcd * 32 + (yy >> 1);          // 0..255
    const size_t rowbase = (size_t)rgrp * 4096;
    const int colbase = chalf * 128;

    // ---- f role: fixed k-octet per thread ----
    const int fo   = tid >> 5;                       // octet 0..31
    const int fcoh = tid >> 7;                       // cohort 0..7 (= fo>>2)
    const int foq  = fo & 3;                         // octet within step
    const int frr  = tid & 31;                       // base row
    const int fidx0 = ((frr >> 4) * 64) + foq * 16 + ((frr & 15) ^ (foq << 2));

    // ---- E role: threads 512..1023, one uint4 each ----
    const bool isE = (tid >= 512);
    const int et   = tid & 511;
    const int erow = et >> 2, eq = et & 3;
    const int eidx = ((erow >> 4) * 64) + eq * 16 + ((erow & 15) ^ (eq << 2));

    // swizzled A-frag read offset
    const int lx = lane ^ ((lane >> 4) << 2);

    // ---- persistent f32 silu-MLP coefficients for my octet (40 VGPR) ----
    float cw[4][8], cb[8];
    {
        const int kb = fo * 8;
        #pragma unroll
        for (int j = 0; j < 4; ++j) {
            float4 a = *(const float4*)(Wf1 + j * 256 + kb);
            float4 b = *(const float4*)(Wf1 + j * 256 + kb + 4);
            cw[j][0]=a.x; cw[j][1]=a.y; cw[j][2]=a.z; cw[j][3]=a.w;
            cw[j][4]=b.x; cw[j][5]=b.y; cw[j][6]=b.z; cw[j][7]=b.w;
        }
        float4 a = *(const float4*)(b1 + kb);
        float4 b = *(const float4*)(b1 + kb + 4);
        cb[0]=a.x; cb[1]=a.y; cb[2]=a.z; cb[3]=a.w;
        cb[4]=b.x; cb[5]=b.y; cb[6]=b.z; cb[7]=b.w;
    }
    float vb2[2], vbn[2];
    #pragma unroll
    for (int n = 0; n < 2; ++n) {
        const int col = colbase + wn * 32 + n * 16 + (lane & 15);
        vb2[n] = b2[col];
        vbn[n] = bnb[col];
    }

    float4 d4r[4];                       // my 4 diff rows (for next activation)
    float4 EnA, EnB, EfA, EfB;           // E prefetch regs (2-step pipeline)

    auto dissue = [&](int s) {           // issue d4 loads for tile s>>3
        const size_t rb = rowbase + (size_t)(s >> 3) * 128;
        #pragma unroll
        for (int m = 0; m < 4; ++m)
            d4r[m] = *(const float4*)(diff + (rb + frr + 32 * m) * 4);
    };
    auto fstage = [&]() {                // compute+write my 32 f values
        #pragma unroll
        for (int m = 0; m < 4; ++m) {
            const float4 d = d4r[m];
            unsigned ov[4];
            #pragma unroll
            for (int p = 0; p < 4; ++p) {
                float pA = cb[2*p]   + d.x*cw[0][2*p]   + d.y*cw[1][2*p]
                                     + d.z*cw[2][2*p]   + d.w*cw[3][2*p];
                float pB = cb[2*p+1] + d.x*cw[0][2*p+1] + d.y*cw[1][2*p+1]
                                     + d.z*cw[2][2*p+1] + d.w*cw[3][2*p+1];
                ov[p] = pkr(silu_f(pA), silu_f(pB));
            }
            uint4 o4; o4.x = ov[0]; o4.y = ov[1]; o4.z = ov[2]; o4.w = ov[3];
            fbuf[fidx0 + m * 128] = o4;
        }
    };
    auto eload = [&](int s, float4& ea, float4& eb) {
        const float* p = nbr + (rowbase + (size_t)(s >> 3) * 128 + erow) * 256
                         + (s & 7) * 32 + eq * 8;
        ea = *(const float4*)p;
        eb = *(const float4*)(p + 4);
    };
    auto ewrite = [&](const float4& ea, const float4& eb) {
        uint4 o;
        o.x = pkr(ea.x, ea.y); o.y = pkr(ea.z, ea.w);
        o.z = pkr(eb.x, eb.y); o.w = pkr(eb.z, eb.w);
        ebuf[eidx] = o;
    };

    // ---- prologue: weights -> LDS, stage step 0, issue step-1 materials ----
    #pragma unroll
    for (int i = 0; i < 4; ++i) {
        int idx = tid + i * 1024;
        int kt = idx >> 9, rem = idx & 511;
        int src = kt * 1024 + chalf * 512 + rem;
        w2l[idx] = wf2_g[src];
        wnl[idx] = wnb_g[src];
    }
    if (isE) { float4 a, b; eload(0, a, b); ewrite(a, b); }
    if (fcoh == 0) { dissue(0); fstage(); }
    __syncthreads();
    if (isE) eload(1, EnA, EnB);
    if (fcoh == 1) dissue(1);

    f32x4 accP[2][2], accH[2][2];
    #pragma unroll
    for (int m = 0; m < 2; ++m)
        #pragma unroll
        for (int n = 0; n < 2; ++n) {
            accP[m][n] = (f32x4){0.f, 0.f, 0.f, 0.f};
            accH[m][n] = (f32x4){0.f, 0.f, 0.f, 0.f};
        }

    const short8* fb8 = (const short8*)fbuf;
    const short8* eb8 = (const short8*)ebuf;
    const short8* w28 = (const short8*)w2l;
    const short8* wn8 = (const short8*)wnl;

    for (int t = 0; t < 32; ++t) {
        #pragma unroll
        for (int kt = 0; kt < 8; ++kt) {
            const int g = t * 8 + kt;
            // phase 0: prefetch issues for step g+2
            if (g + 2 < 256) {
                if (isE) eload(g + 2, EfA, EfB);
                if (((kt + 2) & 7) == fcoh && (g + 2) >> 3 == (g + 2) / 8)
                    ; // (kept trivial; real check below)
                if (((g + 2) & 7) == fcoh) dissue(g + 2);
            }
            // phase 1: A-frag reads (current step)
            short8 aF0 = fb8[(wm * 2 + 0) * 64 + lx];
            short8 aF1 = fb8[(wm * 2 + 1) * 64 + lx];
            short8 aE0 = eb8[(wm * 2 + 0) * 64 + lx];
            short8 aE1 = eb8[(wm * 2 + 1) * 64 + lx];
            // bar1: A reads complete before anyone overwrites staging buffers
            asm volatile("s_waitcnt lgkmcnt(0)" ::: "memory");
            __builtin_amdgcn_sched_barrier(0);
            __builtin_amdgcn_s_barrier();
            // phase 2: B-frag reads (read-only region) + MFMA cluster
            short8 B20 = w28[(kt * 8 + wn * 2 + 0) * 64 + lane];
            short8 B21 = w28[(kt * 8 + wn * 2 + 1) * 64 + lane];
            short8 Bn0 = wn8[(kt * 8 + wn * 2 + 0) * 64 + lane];
            short8 Bn1 = wn8[(kt * 8 + wn * 2 + 1) * 64 + lane];
            accP[0][0] = __builtin_amdgcn_mfma_f32_16x16x32_bf16(aF0, B20, accP[0][0], 0, 0, 0);
            accP[0][1] = __builtin_amdgcn_mfma_f32_16x16x32_bf16(aF0, B21, accP[0][1], 0, 0, 0);
            accP[1][0] = __builtin_amdgcn_mfma_f32_16x16x32_bf16(aF1, B20, accP[1][0], 0, 0, 0);
            accP[1][1] = __builtin_amdgcn_mfma_f32_16x16x32_bf16(aF1, B21, accP[1][1], 0, 0, 0);
            accH[0][0] = __builtin_amdgcn_mfma_f32_16x16x32_bf16(aE0, Bn0, accH[0][0], 0, 0, 0);
            accH[0][1] = __builtin_amdgcn_mfma_f32_16x16x32_bf16(aE0, Bn1, accH[0][1], 0, 0, 0);
            accH[1][0] = __builtin_amdgcn_mfma_f32_16x16x32_bf16(aE1, Bn0, accH[1][0], 0, 0, 0);
            accH[1][1] = __builtin_amdgcn_mfma_f32_16x16x32_bf16(aE1, Bn1, accH[1][1], 0, 0, 0);
            // phase 3: stage step g+1
            if (g + 1 < 256) {
                if (isE) ewrite(EnA, EnB);
                if (((g + 1) & 7) == fcoh) fstage();
            }
            // phase 4: per-tile epilogue (gate + 32-row reduce + store)
            if (kt == 7) {
                const size_t node = (size_t)rgrp * 128 + t * 4 + wm;
                #pragma unroll
                for (int n = 0; n < 2; ++n) {
                    float s = 0.f;
                    #pragma unroll
                    for (int m = 0; m < 2; ++m)
                        #pragma unroll
                        for (int r = 0; r < 4; ++r)
                            s += (accP[m][n][r] + vb2[n]) * (accH[m][n][r] + vbn[n]);
                    s += __shfl_xor(s, 16);
                    s += __shfl_xor(s, 32);
                    if (lane < 16)
                        msg_out[node * 256 + colbase + wn * 32 + n * 16 + lane] = s;
                }
                #pragma unroll
                for (int m = 0; m < 2; ++m)
                    #pragma unroll
                    for (int n = 0; n < 2; ++n) {
                        accP[m][n] = (f32x4){0.f, 0.f, 0.f, 0.f};
                        accH[m][n] = (f32x4){0.f, 0.f, 0.f, 0.f};
                    }
            }
            // bar2: staging writes visible before next step's A reads
            asm volatile("s_waitcnt lgkmcnt(0)" ::: "memory");
            __builtin_amdgcn_sched_barrier(0);
            __builtin_amdgcn_s_barrier();
            // rotate E prefetch regs
            EnA = EfA; EnB = EfB;
        }
    }
}

// ---------------------------------------------------------------------------
// Kernel 3: out = silu(h_center @ Wc + bc + msg), msg lives in `out` already.
// ---------------------------------------------------------------------------
__global__ __launch_bounds__(256) void out_kernel(
        const float* __restrict__ hc,     // [N,256]
        const float* __restrict__ bc,     // [256]
        const uint4* __restrict__ wc_g,   // frag bf16, 8192 uint4
        float* __restrict__ out)          // [N,256], contains msg on entry
{
    __shared__ unsigned short a_s[4 * 2 * 64 * 8];    // 8KB
    __shared__ unsigned short wc_s[2 * 16 * 64 * 8];  // 32KB

    const int tid  = threadIdx.x;
    const int lane = tid & 63;
    const int wn   = tid >> 6;        // 0..3
    const int rblk = blockIdx.x * 64;

    f32x4 acc[4][4];
    #pragma unroll
    for (int mt = 0; mt < 4; ++mt)
        #pragma unroll
        for (int nt = 0; nt < 4; ++nt)
            acc[mt][nt] = (f32x4){0.f, 0.f, 0.f, 0.f};

    uint4* af4 = (uint4*)a_s;
    for (int kt2 = 0; kt2 < 4; ++kt2) {
        {
            int row = tid >> 2, quarter = tid & 3;
            const float* src = hc + (size_t)(rblk + row) * 256 + kt2 * 64 + quarter * 16;
            float4 v0 = *(const float4*)(src + 0);
            float4 v1 = *(const float4*)(src + 4);
            float4 v2 = *(const float4*)(src + 8);
            float4 v3 = *(const float4*)(src + 12);
            uint4 p0, p1;
            p0.x = pk2(v0.x, v0.y); p0.y = pk2(v0.z, v0.w);
            p0.z = pk2(v1.x, v1.y); p0.w = pk2(v1.z, v1.w);
            p1.x = pk2(v2.x, v2.y); p1.y = pk2(v2.z, v2.w);
            p1.z = pk2(v3.x, v3.y); p1.w = pk2(v3.z, v3.w);
            int mt = row >> 4, kti = quarter >> 1, fr = row & 15;
            int g0 = (quarter & 1) * 2;
            af4[(mt * 2 + kti) * 64 + g0 * 16 + fr]       = p0;
            af4[(mt * 2 + kti) * 64 + (g0 + 1) * 16 + fr] = p1;
            const uint4* srcw = wc_g + kt2 * 2048;
            uint4* dw = (uint4*)wc_s;
            #pragma unroll
            for (int j = 0; j < 8; ++j)
                dw[j * 256 + tid] = srcw[j * 256 + tid];
        }
        __syncthreads();
        #pragma unroll
        for (int kti = 0; kti < 2; ++kti) {
            short8 b[4];
            #pragma unroll
            for (int nt = 0; nt < 4; ++nt)
                b[nt] = *(const short8*)&wc_s[((kti * 16 + wn * 4 + nt) * 64 + lane) * 8];
            #pragma unroll
            for (int mt = 0; mt < 4; ++mt) {
                short8 a = *(const short8*)&a_s[((mt * 2 + kti) * 64 + lane) * 8];
                #pragma unroll
                for (int nt = 0; nt < 4; ++nt)
                    acc[mt][nt] = __builtin_amdgcn_mfma_f32_16x16x32_bf16(a, b[nt], acc[mt][nt], 0, 0, 0);
            }
        }
        __syncthreads();
    }

    #pragma unroll
    for (int mt = 0; mt < 4; ++mt)
        #pragma unroll
        for (int nt = 0; nt < 4; ++nt)
            #pragma unroll
            for (int r = 0; r < 4; ++r) {
                int grow = rblk + mt * 16 + ((lane >> 4) << 2) + r;
                int col  = wn * 64 + nt * 16 + (lane & 15);
                size_t idx = (size_t)grow * 256 + col;
                float v = acc[mt][nt][r] + bc[col] + out[idx];
                out[idx] = silu_f(v);
            }
}

// ---------------------------------------------------------------------------
extern "C" void kernel_launch(void* const* d_in, const int* in_sizes, int n_in,
                              void* d_out, int out_size, void* d_ws, size_t ws_size,
                              hipStream_t stream) {
    const float* h_center    = (const float*)d_in[0];
    const float* h_neighbors = (const float*)d_in[1];
    const float* differences = (const float*)d_in[2];
    const float* W_f1        = (const float*)d_in[3];
    const float* b_f1        = (const float*)d_in[4];
    const float* W_f2        = (const float*)d_in[5];
    const float* b_f2        = (const float*)d_in[6];
    const float* W_nb        = (const float*)d_in[7];
    const float* b_nb        = (const float*)d_in[8];
    const float* W_c         = (const float*)d_in[9];
    const float* b_c         = (const float*)d_in[10];
    float* out = (float*)d_out;

    uint4* ws4 = (uint4*)d_ws;            // 24576 * 16B = 384KB of scratch
    const uint4* wf2_ws = ws4;            // [0, 8192)
    const uint4* wnb_ws = ws4 + 8192;     // [8192, 16384)
    const uint4* wc_ws  = ws4 + 16384;    // [16384, 24576)

    prep_weights<<<96, 256, 0, stream>>>(W_f2, W_nb, W_c, ws4);
    msg_kernel<<<512, 1024, 0, stream>>>(
        h_neighbors, differences, W_f1, b_f1, b_f2, b_nb, wf2_ws, wnb_ws, out);
    out_kernel<<<NN / 64, 256, 0, stream>>>(h_center, b_c, wc_ws, out);
}

// Round 8
// 709.878 us; speedup vs baseline: 2.4629x; 2.4629x over previous
//
#include <hip/hip_runtime.h>
#include <hip/hip_bf16.h>
#include <stdint.h>

// Problem constants
#define NN 32768
#define KNBR 32

typedef __attribute__((ext_vector_type(8))) short short8;
typedef __attribute__((ext_vector_type(4))) float f32x4;

__device__ __forceinline__ unsigned int f2bf(float x) {
    union { float f; unsigned int u; } c; c.f = x;
    return (c.u + 0x7FFFu + ((c.u >> 16) & 1u)) >> 16;
}
__device__ __forceinline__ unsigned int pk2(float a, float b) {
    return f2bf(a) | (f2bf(b) << 16);
}
// cheap round-half-up bf16 pack (validated: absmax 0.125 in r2-r7)
__device__ __forceinline__ unsigned int pkr(float a, float b) {
    unsigned ua = __float_as_uint(a) + 0x8000u;
    unsigned ub = __float_as_uint(b) + 0x8000u;
    return (ua >> 16) | (ub & 0xFFFF0000u);
}
__device__ __forceinline__ float silu_f(float x) {
    return x / (1.0f + __expf(-x));
}

// ---------------------------------------------------------------------------
// Kernel 1: convert W_f2, W_nb, W_c (f32 [256][256]) into bf16 MFMA B-frag
// layout: frag q = (kt*16 + ntg)*64 + lane holds
// B[k = kt*32 + (lane>>4)*8 + i][col = ntg*16 + (lane&15)], i=0..7.
// ---------------------------------------------------------------------------
__global__ void prep_weights(const float* __restrict__ Wf2,
                             const float* __restrict__ Wnb,
                             const float* __restrict__ Wc,
                             uint4* __restrict__ ws_out) {
    int t = blockIdx.x * 256 + threadIdx.x;   // 0..24575
    int w = t >> 13;
    int q = t & 8191;
    int kt = q >> 10;
    int nt = (q >> 6) & 15;
    int lane = q & 63;
    int k0 = kt * 32 + ((lane >> 4) << 3);
    int col = nt * 16 + (lane & 15);
    const float* src = (w == 0) ? Wf2 : (w == 1) ? Wnb : Wc;
    const float* p = src + (size_t)k0 * 256 + col;
    uint4 o;
    o.x = pk2(p[0],        p[256]);
    o.y = pk2(p[512],      p[768]);
    o.z = pk2(p[1024],     p[1280]);
    o.w = pk2(p[1536],     p[1792]);
    ws_out[t] = o;
}

// ---------------------------------------------------------------------------
// Kernel 1b: precompute f = silu(diff @ Wf1 + b1) for ALL 1M edge rows,
// written as bf16 MFMA A-fragments:
//   fout[((g128*8 + kt)*8 + mt)*64 + (kgrp*16 + r16)] holds
//   f[row = g128*128 + mt*16 + r16][k = kt*32 + kgrp*8 .. +8]
// Block (256 thr) = (g128, kt); coefs live in 10 float4 regs (L1-broadcast).
// Writes perfectly coalesced (lane-contiguous 16B).
// ---------------------------------------------------------------------------
__global__ __launch_bounds__(256) void prep_f(
        const float* __restrict__ diff,   // [1M, 4]
        const float* __restrict__ Wf1,    // [4,256]
        const float* __restrict__ b1,     // [256]
        uint4* __restrict__ fout)
{
    const int bid  = blockIdx.x;          // g128*8 + kt
    const int kt   = bid & 7;
    const size_t g128 = (size_t)(bid >> 3);
    const int tid  = threadIdx.x;
    const int lane = tid & 63;
    const int wv   = tid >> 6;            // 0..3
    const int kgrp = lane >> 4, r16 = lane & 15;
    const int k0   = kt * 32 + kgrp * 8;

    float4 cwa[4], cwb[4];
    #pragma unroll
    for (int j = 0; j < 4; ++j) {
        cwa[j] = *(const float4*)(Wf1 + j * 256 + k0);
        cwb[j] = *(const float4*)(Wf1 + j * 256 + k0 + 4);
    }
    const float4 cba = *(const float4*)(b1 + k0);
    const float4 cbb = *(const float4*)(b1 + k0 + 4);

    #pragma unroll
    for (int mi = 0; mi < 2; ++mi) {
        const int mt = mi * 4 + wv;
        const size_t row = g128 * 128 + mt * 16 + r16;
        const float4 d = *(const float4*)(diff + row * 4);
        float v0 = cba.x + d.x*cwa[0].x + d.y*cwa[1].x + d.z*cwa[2].x + d.w*cwa[3].x;
        float v1 = cba.y + d.x*cwa[0].y + d.y*cwa[1].y + d.z*cwa[2].y + d.w*cwa[3].y;
        float v2 = cba.z + d.x*cwa[0].z + d.y*cwa[1].z + d.z*cwa[2].z + d.w*cwa[3].z;
        float v3 = cba.w + d.x*cwa[0].w + d.y*cwa[1].w + d.z*cwa[2].w + d.w*cwa[3].w;
        float v4 = cbb.x + d.x*cwb[0].x + d.y*cwb[1].x + d.z*cwb[2].x + d.w*cwb[3].x;
        float v5 = cbb.y + d.x*cwb[0].y + d.y*cwb[1].y + d.z*cwb[2].y + d.w*cwb[3].y;
        float v6 = cbb.z + d.x*cwb[0].z + d.y*cwb[1].z + d.z*cwb[2].z + d.w*cwb[3].z;
        float v7 = cbb.w + d.x*cwb[0].w + d.y*cwb[1].w + d.z*cwb[2].w + d.w*cwb[3].w;
        uint4 o;
        o.x = pkr(silu_f(v0), silu_f(v1));
        o.y = pkr(silu_f(v2), silu_f(v3));
        o.z = pkr(silu_f(v4), silu_f(v5));
        o.w = pkr(silu_f(v6), silu_f(v7));
        fout[(size_t)bid * 512 + mt * 64 + lane] = o;
    }
}

// ---------------------------------------------------------------------------
// Kernel 2: fused edge pipeline. Weights RESIDENT in LDS (r6 pairing: col-half
// pairs of the same rowgroup land on same XCD -> E rows L2-hit on 2nd read).
// 1024 thr = 16 waves (4M x 4N), tile = 128 rows, K-step = 32.
// f A-frags: read DIRECTLY from global (prep_f frag layout; 4 wn-waves read
// identical addresses -> L1 broadcast). E: double-buffered LDS (16KB),
// linear-in-tid writes (0 conflicts), ONE raw barrier per step.
// ---------------------------------------------------------------------------
__global__ __launch_bounds__(1024, 4) void msg_kernel(
        const float* __restrict__ nbr,    // h_neighbors [N*K, 256]
        const float* __restrict__ b2,     // b_f2 [256]
        const float* __restrict__ bnb,    // b_nb [256]
        const uint4* __restrict__ wf2_g,  // frag bf16, 8192 uint4
        const uint4* __restrict__ wnb_g,  // frag bf16, 8192 uint4
        const uint4* __restrict__ ffrag,  // f A-frags (prep_f output)
        float* __restrict__ msg_out)      // [N,256] f32
{
    __shared__ uint4 w2l[4096];        // 64KB  Wf2, this block's 128 cols
    __shared__ uint4 wnl[4096];        // 64KB  Wnb
    __shared__ uint4 ebuf[2][512];     // 16KB  E A-frags, double-buffered

    const int tid  = threadIdx.x;
    const int lane = tid & 63;
    const int wid  = tid >> 6;        // 0..15
    const int wm   = wid >> 2;        // 0..3  (32-row slice)
    const int wn   = wid & 3;         // 0..3  (32-col slice)
    const int xcd  = blockIdx.x & 7;
    const int yy   = blockIdx.x >> 3;
    const int chalf = yy & 1;
    const int rgrp  = xcd * 32 + (yy >> 1);          // 0..255
    const size_t rowbase = (size_t)rgrp * 4096;
    const int colbase = chalf * 128;

    // ---- E staging mapping: tid -> half of frag slot s ----
    const int s    = tid >> 1;        // 0..511
    const int half = tid & 1;
    const int emt  = s >> 6;          // 0..7
    const int ekg  = (s >> 4) & 3;    // k-octet
    const int erow = s & 15;

    auto eload = [&](int g) -> float4 {
        const int t = g >> 3, kt = g & 7;
        return *(const float4*)(nbr + (rowbase + (size_t)t * 128 + emt * 16 + erow) * 256
                                + kt * 32 + ekg * 8 + half * 4);
    };
    auto ewrite = [&](int pb, const float4& v) {
        unsigned lo = pkr(v.x, v.y), hi = pkr(v.z, v.w);
        *(unsigned long long*)((char*)&ebuf[pb][s] + half * 8) =
            ((unsigned long long)hi << 32) | lo;
    };
    // f A-frag loads (global, frag layout; depends only on wm)
    const short8* fbase = (const short8*)ffrag;
    auto fload = [&](int g, short8& a0, short8& a1) {
        const size_t fb = ((size_t)(rgrp * 32 + (g >> 3)) * 8 + (g & 7)) * 512;
        a0 = fbase[fb + (wm * 2 + 0) * 64 + lane];
        a1 = fbase[fb + (wm * 2 + 1) * 64 + lane];
    };

    // ---- prologue: weights -> LDS; stage E step 0; preload pipeline ----
    #pragma unroll
    for (int i = 0; i < 4; ++i) {
        int idx = tid + i * 1024;
        int kt = idx >> 9, rem = idx & 511;
        int src = kt * 1024 + chalf * 512 + rem;
        w2l[idx] = wf2_g[src];
        wnl[idx] = wnb_g[src];
    }
    float vb2[2], vbn[2];
    #pragma unroll
    for (int n = 0; n < 2; ++n) {
        const int col = colbase + wn * 32 + n * 16 + (lane & 15);
        vb2[n] = b2[col];
        vbn[n] = bnb[col];
    }
    ewrite(0, eload(0));
    float4 EnA = eload(1);               // E for step 1 (written during step 0)
    short8 aF0c, aF1c;
    fload(0, aF0c, aF1c);
    __syncthreads();

    f32x4 accP[2][2], accH[2][2];
    #pragma unroll
    for (int m = 0; m < 2; ++m)
        #pragma unroll
        for (int n = 0; n < 2; ++n) {
            accP[m][n] = (f32x4){0.f, 0.f, 0.f, 0.f};
            accH[m][n] = (f32x4){0.f, 0.f, 0.f, 0.f};
        }

    const short8* w28 = (const short8*)w2l;
    const short8* wn8 = (const short8*)wnl;

    for (int t = 0; t < 32; ++t) {
        #pragma unroll
        for (int kt = 0; kt < 8; ++kt) {
            const int g = t * 8 + kt;
            const int pb = g & 1;
            // prefetch: E two steps ahead, f one step ahead (both global)
            float4 EfA;
            if (g + 2 < 256) EfA = eload(g + 2);
            short8 aF0n, aF1n;
            if (g + 1 < 256) fload(g + 1, aF0n, aF1n);
            // A-frag E reads (current buffer)
            const short8* eb8 = (const short8*)ebuf[pb];
            short8 aE0 = eb8[(wm * 2 + 0) * 64 + lane];
            short8 aE1 = eb8[(wm * 2 + 1) * 64 + lane];
            // B reads (read-only LDS region) + MFMA cluster
            short8 B20 = w28[(kt * 8 + wn * 2 + 0) * 64 + lane];
            short8 B21 = w28[(kt * 8 + wn * 2 + 1) * 64 + lane];
            short8 Bn0 = wn8[(kt * 8 + wn * 2 + 0) * 64 + lane];
            short8 Bn1 = wn8[(kt * 8 + wn * 2 + 1) * 64 + lane];
            accP[0][0] = __builtin_amdgcn_mfma_f32_16x16x32_bf16(aF0c, B20, accP[0][0], 0, 0, 0);
            accP[0][1] = __builtin_amdgcn_mfma_f32_16x16x32_bf16(aF0c, B21, accP[0][1], 0, 0, 0);
            accP[1][0] = __builtin_amdgcn_mfma_f32_16x16x32_bf16(aF1c, B20, accP[1][0], 0, 0, 0);
            accP[1][1] = __builtin_amdgcn_mfma_f32_16x16x32_bf16(aF1c, B21, accP[1][1], 0, 0, 0);
            accH[0][0] = __builtin_amdgcn_mfma_f32_16x16x32_bf16(aE0, Bn0, accH[0][0], 0, 0, 0);
            accH[0][1] = __builtin_amdgcn_mfma_f32_16x16x32_bf16(aE0, Bn1, accH[0][1], 0, 0, 0);
            accH[1][0] = __builtin_amdgcn_mfma_f32_16x16x32_bf16(aE1, Bn0, accH[1][0], 0, 0, 0);
            accH[1][1] = __builtin_amdgcn_mfma_f32_16x16x32_bf16(aE1, Bn1, accH[1][1], 0, 0, 0);
            // stage E step g+1 into the OTHER buffer (no race with pb reads)
            if (g + 1 < 256) ewrite(pb ^ 1, EnA);
            // per-tile epilogue: gate + 32-row reduce + store (verified map)
            if (kt == 7) {
                const size_t node = (size_t)rgrp * 128 + t * 4 + wm;
                #pragma unroll
                for (int n = 0; n < 2; ++n) {
                    float sv = 0.f;
                    #pragma unroll
                    for (int m = 0; m < 2; ++m)
                        #pragma unroll
                        for (int r = 0; r < 4; ++r)
                            sv += (accP[m][n][r] + vb2[n]) * (accH[m][n][r] + vbn[n]);
                    sv += __shfl_xor(sv, 16);
                    sv += __shfl_xor(sv, 32);
                    if (lane < 16)
                        msg_out[node * 256 + colbase + wn * 32 + n * 16 + lane] = sv;
                }
                #pragma unroll
                for (int m = 0; m < 2; ++m)
                    #pragma unroll
                    for (int n = 0; n < 2; ++n) {
                        accP[m][n] = (f32x4){0.f, 0.f, 0.f, 0.f};
                        accH[m][n] = (f32x4){0.f, 0.f, 0.f, 0.f};
                    }
            }
            // ONE barrier per step: pb^1 writes visible; pb reads done
            asm volatile("s_waitcnt lgkmcnt(0)" ::: "memory");
            __builtin_amdgcn_sched_barrier(0);
            __builtin_amdgcn_s_barrier();
            EnA = EfA;
            aF0c = aF0n; aF1c = aF1n;
        }
    }
}

// ---------------------------------------------------------------------------
// Kernel 3: out = silu(h_center @ Wc + bc + msg), msg lives in `out` already.
// ---------------------------------------------------------------------------
__global__ __launch_bounds__(256) void out_kernel(
        const float* __restrict__ hc,     // [N,256]
        const float* __restrict__ bc,     // [256]
        const uint4* __restrict__ wc_g,   // frag bf16, 8192 uint4
        float* __restrict__ out)          // [N,256], contains msg on entry
{
    __shared__ unsigned short a_s[4 * 2 * 64 * 8];    // 8KB
    __shared__ unsigned short wc_s[2 * 16 * 64 * 8];  // 32KB

    const int tid  = threadIdx.x;
    const int lane = tid & 63;
    const int wn   = tid >> 6;        // 0..3
    const int rblk = blockIdx.x * 64;

    f32x4 acc[4][4];
    #pragma unroll
    for (int mt = 0; mt < 4; ++mt)
        #pragma unroll
        for (int nt = 0; nt < 4; ++nt)
            acc[mt][nt] = (f32x4){0.f, 0.f, 0.f, 0.f};

    uint4* af4 = (uint4*)a_s;
    for (int kt2 = 0; kt2 < 4; ++kt2) {
        {
            int row = tid >> 2, quarter = tid & 3;
            const float* src = hc + (size_t)(rblk + row) * 256 + kt2 * 64 + quarter * 16;
            float4 v0 = *(const float4*)(src + 0);
            float4 v1 = *(const float4*)(src + 4);
            float4 v2 = *(const float4*)(src + 8);
            float4 v3 = *(const float4*)(src + 12);
            uint4 p0, p1;
            p0.x = pk2(v0.x, v0.y); p0.y = pk2(v0.z, v0.w);
            p0.z = pk2(v1.x, v1.y); p0.w = pk2(v1.z, v1.w);
            p1.x = pk2(v2.x, v2.y); p1.y = pk2(v2.z, v2.w);
            p1.z = pk2(v3.x, v3.y); p1.w = pk2(v3.z, v3.w);
            int mt = row >> 4, kti = quarter >> 1, fr = row & 15;
            int g0 = (quarter & 1) * 2;
            af4[(mt * 2 + kti) * 64 + g0 * 16 + fr]       = p0;
            af4[(mt * 2 + kti) * 64 + (g0 + 1) * 16 + fr] = p1;
            const uint4* srcw = wc_g + kt2 * 2048;
            uint4* dw = (uint4*)wc_s;
            #pragma unroll
            for (int j = 0; j < 8; ++j)
                dw[j * 256 + tid] = srcw[j * 256 + tid];
        }
        __syncthreads();
        #pragma unroll
        for (int kti = 0; kti < 2; ++kti) {
            short8 b[4];
            #pragma unroll
            for (int nt = 0; nt < 4; ++nt)
                b[nt] = *(const short8*)&wc_s[((kti * 16 + wn * 4 + nt) * 64 + lane) * 8];
            #pragma unroll
            for (int mt = 0; mt < 4; ++mt) {
                short8 a = *(const short8*)&a_s[((mt * 2 + kti) * 64 + lane) * 8];
                #pragma unroll
                for (int nt = 0; nt < 4; ++nt)
                    acc[mt][nt] = __builtin_amdgcn_mfma_f32_16x16x32_bf16(a, b[nt], acc[mt][nt], 0, 0, 0);
            }
        }
        __syncthreads();
    }

    #pragma unroll
    for (int mt = 0; mt < 4; ++mt)
        #pragma unroll
        for (int nt = 0; nt < 4; ++nt)
            #pragma unroll
            for (int r = 0; r < 4; ++r) {
                int grow = rblk + mt * 16 + ((lane >> 4) << 2) + r;
                int col  = wn * 64 + nt * 16 + (lane & 15);
                size_t idx = (size_t)grow * 256 + col;
                float v = acc[mt][nt][r] + bc[col] + out[idx];
                out[idx] = silu_f(v);
            }
}

// ---------------------------------------------------------------------------
extern "C" void kernel_launch(void* const* d_in, const int* in_sizes, int n_in,
                              void* d_out, int out_size, void* d_ws, size_t ws_size,
                              hipStream_t stream) {
    const float* h_center    = (const float*)d_in[0];
    const float* h_neighbors = (const float*)d_in[1];
    const float* differences = (const float*)d_in[2];
    const float* W_f1        = (const float*)d_in[3];
    const float* b_f1        = (const float*)d_in[4];
    const float* W_f2        = (const float*)d_in[5];
    const float* b_f2        = (const float*)d_in[6];
    const float* W_nb        = (const float*)d_in[7];
    const float* b_nb        = (const float*)d_in[8];
    const float* W_c         = (const float*)d_in[9];
    const float* b_c         = (const float*)d_in[10];
    float* out = (float*)d_out;

    uint4* ws4 = (uint4*)d_ws;
    const uint4* wf2_ws = ws4;            // [0, 8192)
    const uint4* wnb_ws = ws4 + 8192;     // [8192, 16384)
    const uint4* wc_ws  = ws4 + 16384;    // [16384, 24576)
    uint4* f_ws         = ws4 + 24576;    // 4,194,304 uint4 = 67MB

    prep_weights<<<96, 256, 0, stream>>>(W_f2, W_nb, W_c, ws4);
    prep_f<<<65536, 256, 0, stream>>>(differences, W_f1, b_f1, f_ws);
    msg_kernel<<<512, 1024, 0, stream>>>(
        h_neighbors, b_f2, b_nb, wf2_ws, wnb_ws, f_ws, out);
    out_kernel<<<NN / 64, 256, 0, stream>>>(h_center, b_c, wc_ws, out);
}